// Round 1
// baseline (133002.588 us; speedup 1.0000x reference)
//
#include <hip/hip_runtime.h>
#include <math.h>

#define DD    1024
#define BB    16
#define TT    1024
#define NSLOT 64
#define SCALE_F 0.03125f   // 1/sqrt(1024)

// =====================================================================
// fp32 tiled GEMM: C[M,N] = A[M,K] @ (BT ? B[N,K]^T : B[K,N])
// EPI: 0 = none, 1 = silu
// BM=BN=64, BK=32, 256 threads, 4x4 micro-tile
// =====================================================================
template<bool BT, int EPI>
__global__ __launch_bounds__(256) void gemm_nt(const float* __restrict__ A,
                                               const float* __restrict__ Bm,
                                               float* __restrict__ C,
                                               int M, int N, int K) {
  __shared__ float As[32][68];
  __shared__ float Bs[32][68];
  const int tid = threadIdx.x;
  const int n0 = blockIdx.x * 64;
  const int m0 = blockIdx.y * 64;
  const int i0 = (tid >> 4) * 4;
  const int j0 = (tid & 15) * 4;
  float acc[4][4] = {};

  for (int k0 = 0; k0 < K; k0 += 32) {
    // A tile: 64 rows x 32 k, transposed into As[kk][r]
#pragma unroll
    for (int s = 0; s < 2; ++s) {
      int id = tid + 256 * s;
      int r = id >> 3, c4 = id & 7;
      float4 v = *(const float4*)&A[(size_t)(m0 + r) * K + k0 + c4 * 4];
      As[c4 * 4 + 0][r] = v.x; As[c4 * 4 + 1][r] = v.y;
      As[c4 * 4 + 2][r] = v.z; As[c4 * 4 + 3][r] = v.w;
    }
    if (BT) {
#pragma unroll
      for (int s = 0; s < 2; ++s) {
        int id = tid + 256 * s;
        int r = id >> 3, c4 = id & 7;
        float4 v = *(const float4*)&Bm[(size_t)(n0 + r) * K + k0 + c4 * 4];
        Bs[c4 * 4 + 0][r] = v.x; Bs[c4 * 4 + 1][r] = v.y;
        Bs[c4 * 4 + 2][r] = v.z; Bs[c4 * 4 + 3][r] = v.w;
      }
    } else {
#pragma unroll
      for (int s = 0; s < 2; ++s) {
        int id = tid + 256 * s;
        int kk = id >> 4, c4 = id & 15;
        float4 v = *(const float4*)&Bm[(size_t)(k0 + kk) * N + n0 + c4 * 4];
        *(float4*)&Bs[kk][c4 * 4] = v;
      }
    }
    __syncthreads();
#pragma unroll
    for (int kk = 0; kk < 32; ++kk) {
      float4 a = *(const float4*)&As[kk][i0];
      float4 b = *(const float4*)&Bs[kk][j0];
      float av[4] = {a.x, a.y, a.z, a.w};
      float bv[4] = {b.x, b.y, b.z, b.w};
#pragma unroll
      for (int ii = 0; ii < 4; ++ii)
#pragma unroll
        for (int jj = 0; jj < 4; ++jj)
          acc[ii][jj] = fmaf(av[ii], bv[jj], acc[ii][jj]);
    }
    __syncthreads();
  }

#pragma unroll
  for (int ii = 0; ii < 4; ++ii) {
    float4 v;
    float* vp = (float*)&v;
#pragma unroll
    for (int jj = 0; jj < 4; ++jj) {
      float x = acc[ii][jj];
      if (EPI == 1) x = x / (1.0f + __expf(-x));   // silu
      vp[jj] = x;
    }
    *(float4*)&C[(size_t)(m0 + i0 + ii) * N + n0 + j0] = v;
  }
}

// =====================================================================
// Device-scope grid barrier (manual; 256 co-resident workgroups)
// =====================================================================
__device__ __forceinline__ void gbar(int* cnt, int* gen) {
  __syncthreads();
  if (threadIdx.x == 0) {
    __threadfence();   // release: make our writes device-visible
    int g = __hip_atomic_load(gen, __ATOMIC_RELAXED, __HIP_MEMORY_SCOPE_AGENT);
    int a = __hip_atomic_fetch_add(cnt, 1, __ATOMIC_ACQ_REL, __HIP_MEMORY_SCOPE_AGENT);
    if (a == 255) {
      __hip_atomic_store(cnt, 0, __ATOMIC_RELAXED, __HIP_MEMORY_SCOPE_AGENT);
      __hip_atomic_fetch_add(gen, 1, __ATOMIC_RELEASE, __HIP_MEMORY_SCOPE_AGENT);
    } else {
      while (__hip_atomic_load(gen, __ATOMIC_RELAXED, __HIP_MEMORY_SCOPE_AGENT) == g)
        __builtin_amdgcn_s_sleep(1);
    }
    __threadfence();   // acquire: invalidate stale cache lines
  }
  __syncthreads();
}

// =====================================================================
// Persistent scan kernel: 256 wgs x 256 threads.
// wg owns: e-rows [4*wg, 4*wg+4) of W_h / W_write / h; tape pairs
// (b = wg>>4, n in [(wg&15)*4, +4)).
// Per step: PhaseH (h(k)=tanh(...)), PhaseM (Rh(k+1), wv(k), scores_w),
// PhaseU (tape lerp + scores_r(k+1) fused).
// =====================================================================
__global__ __launch_bounds__(256, 1) void scan_kernel(
    const float* __restrict__ W_h, const float* __restrict__ W_wr,
    const float* __restrict__ b_h, const float* __restrict__ gate,
    float* __restrict__ wx,      // [B][T][D]; overwritten in place with h*gate
    float* __restrict__ wv,      // [B][D]
    float* __restrict__ s_w,     // [B][NSLOT]
    float* __restrict__ s_r,     // [NSLOT][B]  (n-major for conflict-free LDS)
    float* __restrict__ h,       // [B][D]      (d_out h_work_f slot)
    float* __restrict__ tape,    // [B][NSLOT][D] (d_out h_tape_f slot)
    int* __restrict__ bar) {
  const int tid = threadIdx.x;
  const int wg  = blockIdx.x;
  const int e0  = wg * 4;
  const int pb  = wg >> 4;
  const int n0  = (wg & 15) * 4;

  __shared__ float Rh_lds[64];    // [b*4 + ei]
  __shared__ float sc_lds[1024];  // scores_r staging, [n*16 + b]
  __shared__ float m_lds[16], si_lds[16];
  __shared__ float wv_lds[1024];
  __shared__ float sw_lds[64];
  __shared__ float red_lds[16];

  for (int k = 0; k < TT; ++k) {
    // ---------------- Phase H : h(k) ----------------
    if (k > 0) {
      for (int i = tid; i < 1024; i += 256) sc_lds[i] = s_r[i];
    }
    __syncthreads();
    if (k > 0 && tid < 16) {
      int b = tid;
      float m = -1e30f;
      for (int n = 0; n < 64; ++n) m = fmaxf(m, sc_lds[n * 16 + b]);
      float s = 0.0f;
      for (int n = 0; n < 64; ++n) s += __expf(sc_lds[n * 16 + b] - m);
      m_lds[b] = m; si_lds[b] = 1.0f / s;
    }
    __syncthreads();
    {
      int item = tid >> 2;          // 0..63 : (b, ei)
      int s4   = tid & 3;           // n-quarter
      int b    = item >> 2;
      int ei   = item & 3;
      int e    = e0 + ei;
      float red = 0.0f;
      if (k > 0) {
        float m = m_lds[b], si = si_lds[b];
#pragma unroll
        for (int i = 0; i < 16; ++i) {
          int n = s4 * 16 + i;
          float attn = __expf(sc_lds[n * 16 + b] - m) * si;
          red = fmaf(attn, tape[(size_t)(b * 64 + n) * 1024 + e], red);
        }
      }
      red += __shfl_xor(red, 1);
      red += __shfl_xor(red, 2);
      if (s4 == 0) {
        size_t xi = (size_t)(b * 1024 + k) * 1024 + e;
        float val = (k > 0 ? Rh_lds[item] : 0.0f) + wx[xi] + red + b_h[e];
        float hv = tanhf(val);
        h[b * 1024 + e] = hv;
        wx[xi] = hv * gate[xi];      // gated output row, in place
      }
    }
    gbar(bar, bar + 1);

    // ---------------- Phase M : Rh(k+1), wv(k), scores_w(k) ----------------
    {
      int g = tid >> 4;          // batch
      int c = tid & 15;          // d-interleave: d = 4c + 64i
      const float* hb = &h[g * 1024 + 4 * c];
      float hreg[64];
#pragma unroll
      for (int i = 0; i < 16; ++i)
        *(float4*)&hreg[4 * i] = *(const float4*)&hb[64 * i];
      float acc[8] = {0, 0, 0, 0, 0, 0, 0, 0};
#pragma unroll
      for (int r = 0; r < 4; ++r) {
        const float* wp = &W_h[(size_t)(e0 + r) * 1024 + 4 * c];
        float a = 0.0f;
#pragma unroll
        for (int i = 0; i < 16; ++i) {
          float4 w = *(const float4*)&wp[64 * i];
          a = fmaf(w.x, hreg[4 * i + 0], a);
          a = fmaf(w.y, hreg[4 * i + 1], a);
          a = fmaf(w.z, hreg[4 * i + 2], a);
          a = fmaf(w.w, hreg[4 * i + 3], a);
        }
        acc[r] = a;
      }
#pragma unroll
      for (int r = 0; r < 4; ++r) {
        const float* wp = &W_wr[(size_t)(e0 + r) * 1024 + 4 * c];
        float a = 0.0f;
#pragma unroll
        for (int i = 0; i < 16; ++i) {
          float4 w = *(const float4*)&wp[64 * i];
          a = fmaf(w.x, hreg[4 * i + 0], a);
          a = fmaf(w.y, hreg[4 * i + 1], a);
          a = fmaf(w.z, hreg[4 * i + 2], a);
          a = fmaf(w.w, hreg[4 * i + 3], a);
        }
        acc[4 + r] = a;
      }
#pragma unroll
      for (int r = 0; r < 8; ++r) {
        acc[r] += __shfl_xor(acc[r], 1);
        acc[r] += __shfl_xor(acc[r], 2);
        acc[r] += __shfl_xor(acc[r], 4);
        acc[r] += __shfl_xor(acc[r], 8);
      }
      if (c == 0) {
#pragma unroll
        for (int r = 0; r < 4; ++r) Rh_lds[g * 4 + r] = acc[r];
#pragma unroll
        for (int r = 0; r < 4; ++r) wv[g * 1024 + e0 + r] = acc[4 + r];
      }
    }
    {   // write-scores vs OLD tape
      int q = tid >> 6, j = tid & 63;
      int n = n0 + q;
      float s = 0.0f;
      if (k > 0) {
        const float* tp = &tape[(size_t)(pb * 64 + n) * 1024];
        const float* hp = &h[pb * 1024];
#pragma unroll
        for (int i = 0; i < 16; ++i)
          s = fmaf(tp[j + 64 * i], hp[j + 64 * i], s);
      }
#pragma unroll
      for (int off = 32; off >= 1; off >>= 1) s += __shfl_xor(s, off);
      if (j == 0) s_w[pb * 64 + n] = s * SCALE_F;
    }
    gbar(bar, bar + 1);

    // ---------------- Phase U : tape(k) + scores_r(k+1) ----------------
    {
      for (int i = tid; i < 1024; i += 256) wv_lds[i] = wv[pb * 1024 + i];
      if (tid < 64) sw_lds[tid] = s_w[pb * 64 + tid];
      __syncthreads();
      float m = -1e30f;
      for (int n = 0; n < 64; ++n) m = fmaxf(m, sw_lds[n]);
      float ssum = 0.0f;
      for (int n = 0; n < 64; ++n) ssum += __expf(sw_lds[n] - m);
      float inv = 1.0f / ssum;
      float4 hh  = *(const float4*)&h[pb * 1024 + 4 * tid];
      float4 wvv = *(const float4*)&wv_lds[4 * tid];
      float sd[4];
#pragma unroll
      for (int q = 0; q < 4; ++q) {
        int n = n0 + q;
        float wa = __expf(sw_lds[n] - m) * inv;
        float om = 1.0f - wa;
        float* tp = &tape[(size_t)(pb * 64 + n) * 1024 + 4 * tid];
        float4 told;
        if (k > 0) told = *(const float4*)tp;
        else { told.x = 0; told.y = 0; told.z = 0; told.w = 0; }
        float4 tn;
        tn.x = om * told.x + wa * wvv.x;
        tn.y = om * told.y + wa * wvv.y;
        tn.z = om * told.z + wa * wvv.z;
        tn.w = om * told.w + wa * wvv.w;
        *(float4*)tp = tn;
        sd[q] = hh.x * tn.x + hh.y * tn.y + hh.z * tn.z + hh.w * tn.w;
      }
#pragma unroll
      for (int q = 0; q < 4; ++q) {
#pragma unroll
        for (int off = 32; off >= 1; off >>= 1) sd[q] += __shfl_xor(sd[q], off);
      }
      int wid = tid >> 6, lane = tid & 63;
      if (lane == 0) {
        red_lds[wid * 4 + 0] = sd[0]; red_lds[wid * 4 + 1] = sd[1];
        red_lds[wid * 4 + 2] = sd[2]; red_lds[wid * 4 + 3] = sd[3];
      }
      __syncthreads();
      if (tid < 4) {
        float t = red_lds[tid] + red_lds[4 + tid] + red_lds[8 + tid] + red_lds[12 + tid];
        s_r[(n0 + tid) * 16 + pb] = t * SCALE_F;   // n-major layout
      }
    }
    gbar(bar, bar + 1);
  }
}

// =====================================================================
extern "C" void kernel_launch(void* const* d_in, const int* in_sizes, int n_in,
                              void* d_out, int out_size, void* d_ws, size_t ws_size,
                              hipStream_t stream) {
  (void)in_sizes; (void)n_in; (void)out_size; (void)ws_size;
  const float* x      = (const float*)d_in[0];
  const float* in_w   = (const float*)d_in[1];
  const float* out_w  = (const float*)d_in[2];
  const float* gate_w = (const float*)d_in[3];
  const float* W_x    = (const float*)d_in[4];
  const float* W_h    = (const float*)d_in[5];
  const float* W_wr   = (const float*)d_in[6];
  const float* b_h    = (const float*)d_in[7];

  float* out  = (float*)d_out;                     // [16][1024][1024]
  float* tape = out + (size_t)16 * 1024 * 1024;    // [16][64][1024]
  float* hfin = tape + (size_t)16 * 64 * 1024;     // [16][1024]

  float* ws = (float*)d_ws;
  // ws[0 : 1M)  = M1 (dead after wx GEMM), then reused for wv/scores/barrier
  // ws[1M : 17M) = wx_all (becomes gated-h in place)
  float* M1  = ws;
  float* wx  = ws + (1 << 20);
  float* wv  = ws;                  // 16384 floats
  float* s_w = ws + 16384;          // 1024
  float* s_r = ws + 17408;          // 1024
  int*   bar = (int*)(ws + 18432);  // 2 ints

  float* gate = out;                // park gate in d_out output region

  dim3 blk(256);
  // M1 = W_x @ in_proj_w   [1024,1024] (B not transposed)
  gemm_nt<false, 0><<<dim3(16, 16), blk, 0, stream>>>(W_x, in_w, M1, 1024, 1024, 1024);
  // gate = silu(x @ gate_proj_w^T)  -> d_out region
  gemm_nt<true, 1><<<dim3(16, 256), blk, 0, stream>>>(x, gate_w, gate, 16384, 1024, 1024);
  // wx_all = x @ M1^T
  gemm_nt<true, 0><<<dim3(16, 256), blk, 0, stream>>>(x, M1, wx, 16384, 1024, 1024);
  // barrier state (M1 region is dead now)
  hipMemsetAsync(bar, 0, 2 * sizeof(int), stream);
  // sequential scan (persistent, 256 co-resident wgs)
  scan_kernel<<<256, 256, 0, stream>>>(W_h, W_wr, b_h, gate, wx, wv, s_w, s_r,
                                       hfin, tape, bar);
  // output = (h_all * gate) @ out_proj_w^T
  gemm_nt<true, 0><<<dim3(16, 256), blk, 0, stream>>>(wx, out_w, out, 16384, 1024, 1024);
}

// Round 2
// 82294.171 us; speedup vs baseline: 1.6162x; 1.6162x over previous
//
#include <hip/hip_runtime.h>
#include <math.h>

#define SCALE_F 0.03125f   // 1/sqrt(1024)

// =====================================================================
// fp32 tiled GEMM: C[M,N] = A[M,K] @ (BT ? B[N,K]^T : B[K,N])
// EPI: 0 = none, 1 = silu
// =====================================================================
template<bool BT, int EPI>
__global__ __launch_bounds__(256) void gemm_nt(const float* __restrict__ A,
                                               const float* __restrict__ Bm,
                                               float* __restrict__ C,
                                               int M, int N, int K) {
  __shared__ float As[32][68];
  __shared__ float Bs[32][68];
  const int tid = threadIdx.x;
  const int n0 = blockIdx.x * 64;
  const int m0 = blockIdx.y * 64;
  const int i0 = (tid >> 4) * 4;
  const int j0 = (tid & 15) * 4;
  float acc[4][4] = {};

  for (int k0 = 0; k0 < K; k0 += 32) {
#pragma unroll
    for (int s = 0; s < 2; ++s) {
      int id = tid + 256 * s;
      int r = id >> 3, c4 = id & 7;
      float4 v = *(const float4*)&A[(size_t)(m0 + r) * K + k0 + c4 * 4];
      As[c4 * 4 + 0][r] = v.x; As[c4 * 4 + 1][r] = v.y;
      As[c4 * 4 + 2][r] = v.z; As[c4 * 4 + 3][r] = v.w;
    }
    if (BT) {
#pragma unroll
      for (int s = 0; s < 2; ++s) {
        int id = tid + 256 * s;
        int r = id >> 3, c4 = id & 7;
        float4 v = *(const float4*)&Bm[(size_t)(n0 + r) * K + k0 + c4 * 4];
        Bs[c4 * 4 + 0][r] = v.x; Bs[c4 * 4 + 1][r] = v.y;
        Bs[c4 * 4 + 2][r] = v.z; Bs[c4 * 4 + 3][r] = v.w;
      }
    } else {
#pragma unroll
      for (int s = 0; s < 2; ++s) {
        int id = tid + 256 * s;
        int kk = id >> 4, c4 = id & 15;
        float4 v = *(const float4*)&Bm[(size_t)(k0 + kk) * N + n0 + c4 * 4];
        *(float4*)&Bs[kk][c4 * 4] = v;
      }
    }
    __syncthreads();
#pragma unroll
    for (int kk = 0; kk < 32; ++kk) {
      float4 a = *(const float4*)&As[kk][i0];
      float4 b = *(const float4*)&Bs[kk][j0];
      float av[4] = {a.x, a.y, a.z, a.w};
      float bv[4] = {b.x, b.y, b.z, b.w};
#pragma unroll
      for (int ii = 0; ii < 4; ++ii)
#pragma unroll
        for (int jj = 0; jj < 4; ++jj)
          acc[ii][jj] = fmaf(av[ii], bv[jj], acc[ii][jj]);
    }
    __syncthreads();
  }

#pragma unroll
  for (int ii = 0; ii < 4; ++ii) {
    float4 v;
    float* vp = (float*)&v;
#pragma unroll
    for (int jj = 0; jj < 4; ++jj) {
      float x = acc[ii][jj];
      if (EPI == 1) x = x / (1.0f + __expf(-x));
      vp[jj] = x;
    }
    *(float4*)&C[(size_t)(m0 + i0 + ii) * N + n0 + j0] = v;
  }
}

// =====================================================================
// Device-scope grid barrier (256 co-resident workgroups)
// =====================================================================
__device__ __forceinline__ void gbar(int* cnt, int* gen) {
  __syncthreads();
  if (threadIdx.x == 0) {
    __threadfence();
    int g = __hip_atomic_load(gen, __ATOMIC_RELAXED, __HIP_MEMORY_SCOPE_AGENT);
    int a = __hip_atomic_fetch_add(cnt, 1, __ATOMIC_ACQ_REL, __HIP_MEMORY_SCOPE_AGENT);
    if (a == 255) {
      __hip_atomic_store(cnt, 0, __ATOMIC_RELAXED, __HIP_MEMORY_SCOPE_AGENT);
      __hip_atomic_fetch_add(gen, 1, __ATOMIC_RELEASE, __HIP_MEMORY_SCOPE_AGENT);
    } else {
      while (__hip_atomic_load(gen, __ATOMIC_RELAXED, __HIP_MEMORY_SCOPE_AGENT) == g)
        __builtin_amdgcn_s_sleep(1);
    }
    __threadfence();
  }
  __syncthreads();
}

// =====================================================================
// Persistent scan: 256 wgs x 256 threads, 1 wg/CU.
// Tape role: wg -> (b = wg>>4, es = wg&15), tape[b][64 n][64 e-slice] in LDS.
// Matvec role: wg owns rows [4wg,4wg+4) of W_h AND W_write, in REGISTERS
//   (wave v: 2 rows of (v<2 ? W_h : W_wr); lane owns 16-float d-slice).
// Phases per step: P2 (s_r reduce, gather, h=tanh), P3 (matvecs + s_w
// partials), P4 (s_w reduce, tape lerp, s_r partials). 3 grid barriers.
// =====================================================================
__global__ __launch_bounds__(256, 1) void scan_kernel(
    const float* __restrict__ W_h, const float* __restrict__ W_wr,
    const float* __restrict__ b_h, const float* __restrict__ gate,
    float* __restrict__ wx,      // [B][T][D]; overwritten with h*gate
    float* __restrict__ Rh_g,    // [B][D]
    float* __restrict__ wv_g,    // [B][D]
    float* __restrict__ p_r,     // [B][16][64] score partials (read)
    float* __restrict__ p_w,     // [B][16][64] score partials (write)
    float* __restrict__ h_g,     // [B][D] (= d_out h_work_f slot)
    float* __restrict__ tape_out,// [B][64][D]
    int* __restrict__ bar) {
  const int tid  = threadIdx.x;
  const int wg   = blockIdx.x;
  const int wave = tid >> 6;
  const int lane = tid & 63;
  const int pb   = wg >> 4;
  const int es   = wg & 15;
  const int E0   = es * 64;

  __shared__ float tape_l[64][68];   // [n][e], padded
  __shared__ float h_half[8 * 1024]; // staged h for 8 batches
  __shared__ float red[1024];        // partial-reduce staging [es][n]
  __shared__ float gath[256];        // gather partials [nq][e]
  __shared__ float attn_l[64];
  __shared__ float h_own[64];
  __shared__ float wv_own[64];

  // ---- weight preload into registers (once) ----
  const float* Wmat = (wave < 2) ? W_h : W_wr;
  const int r0 = wg * 4 + (wave & 1) * 2;
  float w0[16], w1[16];
#pragma unroll
  for (int j = 0; j < 4; ++j) {
    *(float4*)&w0[4 * j] = *(const float4*)&Wmat[(size_t)r0 * 1024 + lane * 16 + 4 * j];
    *(float4*)&w1[4 * j] = *(const float4*)&Wmat[(size_t)(r0 + 1) * 1024 + lane * 16 + 4 * j];
  }

  // ---- zero init (ws/d_out are poisoned) ----
  for (int i = tid; i < 64 * 68; i += 256) (&tape_l[0][0])[i] = 0.0f;
  if (tid < 64) {
    h_own[tid] = 0.0f;
    h_g[pb * 1024 + E0 + tid] = 0.0f;
    p_r[((size_t)pb * 16 + es) * 64 + tid] = 0.0f;
    int b = tid >> 2, r = tid & 3;
    Rh_g[b * 1024 + wg * 4 + r] = 0.0f;
  }
  gbar(bar, bar + 1);

  for (int k = 0; k < 1024; ++k) {
    // ================= P2: h(k) =================
    {
      float4 v = ((const float4*)(p_r + (size_t)pb * 1024))[tid];
      ((float4*)red)[tid] = v;
    }
    __syncthreads();
    if (wave == 0) {
      float s = 0.0f;
#pragma unroll
      for (int e2 = 0; e2 < 16; ++e2) s += red[e2 * 64 + lane];
      s *= SCALE_F;
      float m = s;
#pragma unroll
      for (int off = 1; off < 64; off <<= 1) m = fmaxf(m, __shfl_xor(m, off));
      float ex = __expf(s - m);
      float sum = ex;
#pragma unroll
      for (int off = 1; off < 64; off <<= 1) sum += __shfl_xor(sum, off);
      attn_l[lane] = ex / sum;
    }
    __syncthreads();
    {
      int e = tid & 63, nq = tid >> 6;
      float g = 0.0f;
#pragma unroll
      for (int i = 0; i < 16; ++i) {
        int n = nq * 16 + i;
        g = fmaf(attn_l[n], tape_l[n][e], g);
      }
      gath[nq * 64 + e] = g;
    }
    __syncthreads();
    if (wave == 0) {
      int eg = E0 + lane;
      size_t xi = ((size_t)pb * 1024 + k) * 1024 + eg;
      float rd = gath[lane] + gath[64 + lane] + gath[128 + lane] + gath[192 + lane];
      float val = Rh_g[pb * 1024 + eg] + wx[xi] + rd + b_h[eg];
      float hv = tanhf(val);
      h_own[lane] = hv;
      h_g[pb * 1024 + eg] = hv;
      wx[xi] = hv * gate[xi];
    }
    gbar(bar, bar + 1);

    // ================= P3: matvecs + s_w partials =================
    {
      int n = tid >> 2, eq = tid & 3;
      float s = 0.0f;
#pragma unroll
      for (int j = 0; j < 16; ++j) {
        int e = eq * 16 + j;
        s = fmaf(tape_l[n][e], h_own[e], s);
      }
      s += __shfl_xor(s, 1);
      s += __shfl_xor(s, 2);
      if (eq == 0) p_w[((size_t)pb * 16 + es) * 64 + n] = s;
    }
    float accA[16], accB[16];
#pragma unroll
    for (int b = 0; b < 16; ++b) { accA[b] = 0.0f; accB[b] = 0.0f; }
    for (int half = 0; half < 2; ++half) {
      __syncthreads();
#pragma unroll
      for (int i = 0; i < 8; ++i) {
        int fi = tid + i * 256;
        ((float4*)h_half)[fi] = ((const float4*)(h_g + half * 8192))[fi];
      }
      __syncthreads();
#pragma unroll
      for (int b8 = 0; b8 < 8; ++b8) {
        const float* hb = &h_half[b8 * 1024 + lane * 16];
        int b = half * 8 + b8;
#pragma unroll
        for (int j4 = 0; j4 < 4; ++j4) {
          float4 hx = *(const float4*)&hb[4 * j4];
          float a = accA[b], c = accB[b];
          a = fmaf(w0[4 * j4 + 0], hx.x, a); a = fmaf(w0[4 * j4 + 1], hx.y, a);
          a = fmaf(w0[4 * j4 + 2], hx.z, a); a = fmaf(w0[4 * j4 + 3], hx.w, a);
          c = fmaf(w1[4 * j4 + 0], hx.x, c); c = fmaf(w1[4 * j4 + 1], hx.y, c);
          c = fmaf(w1[4 * j4 + 2], hx.z, c); c = fmaf(w1[4 * j4 + 3], hx.w, c);
          accA[b] = a; accB[b] = c;
        }
      }
    }
#pragma unroll
    for (int off = 1; off < 64; off <<= 1) {
#pragma unroll
      for (int b = 0; b < 16; ++b) {
        accA[b] += __shfl_xor(accA[b], off);
        accB[b] += __shfl_xor(accB[b], off);
      }
    }
    if (lane == 0) {
      float* dst = (wave < 2) ? Rh_g : wv_g;
#pragma unroll
      for (int b = 0; b < 16; ++b) {
        dst[b * 1024 + r0]     = accA[b];
        dst[b * 1024 + r0 + 1] = accB[b];
      }
    }
    gbar(bar, bar + 1);

    // ================= P4: tape lerp + s_r(k+1) partials =================
    {
      float4 v = ((const float4*)(p_w + (size_t)pb * 1024))[tid];
      ((float4*)red)[tid] = v;
    }
    __syncthreads();
    if (wave == 0) {
      float s = 0.0f;
#pragma unroll
      for (int e2 = 0; e2 < 16; ++e2) s += red[e2 * 64 + lane];
      s *= SCALE_F;
      float m = s;
#pragma unroll
      for (int off = 1; off < 64; off <<= 1) m = fmaxf(m, __shfl_xor(m, off));
      float ex = __expf(s - m);
      float sum = ex;
#pragma unroll
      for (int off = 1; off < 64; off <<= 1) sum += __shfl_xor(sum, off);
      attn_l[lane] = ex / sum;
    } else if (wave == 1) {
      wv_own[lane] = wv_g[pb * 1024 + E0 + lane];
    }
    __syncthreads();
    {
      int e = tid & 63, nq = tid >> 6;
      float wvv = wv_own[e];
#pragma unroll
      for (int i = 0; i < 16; ++i) {
        int n = nq * 16 + i;
        float wa = attn_l[n];
        float t = tape_l[n][e];
        tape_l[n][e] = (1.0f - wa) * t + wa * wvv;
      }
    }
    __syncthreads();
    {
      int n = tid >> 2, eq = tid & 3;
      float s = 0.0f;
#pragma unroll
      for (int j = 0; j < 16; ++j) {
        int e = eq * 16 + j;
        s = fmaf(tape_l[n][e], h_own[e], s);
      }
      s += __shfl_xor(s, 1);
      s += __shfl_xor(s, 2);
      if (eq == 0) p_r[((size_t)pb * 16 + es) * 64 + n] = s;
    }
    gbar(bar, bar + 1);
  }

  // ---- epilogue: dump LDS tape to d_out ----
  {
    int e = tid & 63, nq = tid >> 6;
#pragma unroll
    for (int i = 0; i < 16; ++i) {
      int n = nq * 16 + i;
      tape_out[((size_t)(pb * 64 + n)) * 1024 + E0 + e] = tape_l[n][e];
    }
  }
}

// =====================================================================
extern "C" void kernel_launch(void* const* d_in, const int* in_sizes, int n_in,
                              void* d_out, int out_size, void* d_ws, size_t ws_size,
                              hipStream_t stream) {
  (void)in_sizes; (void)n_in; (void)out_size; (void)ws_size;
  const float* x      = (const float*)d_in[0];
  const float* in_w   = (const float*)d_in[1];
  const float* out_w  = (const float*)d_in[2];
  const float* gate_w = (const float*)d_in[3];
  const float* W_x    = (const float*)d_in[4];
  const float* W_h    = (const float*)d_in[5];
  const float* W_wr   = (const float*)d_in[6];
  const float* b_h    = (const float*)d_in[7];

  float* out  = (float*)d_out;                     // [16][1024][1024]
  float* tape = out + (size_t)16 * 1024 * 1024;    // [16][64][1024]
  float* hfin = tape + (size_t)16 * 64 * 1024;     // [16][1024]

  float* ws = (float*)d_ws;
  // small exchange buffers live in the first 1M floats (M1's region; M1 is
  // dead before the scan starts)
  float* Rh_g = ws;                  // 16384
  float* wv_g = ws + 16384;          // 16384
  float* p_r  = ws + 32768;          // 16384
  float* p_w  = ws + 49152;          // 16384
  int*   bar  = (int*)(ws + 65536);  // 2 ints
  float* M1   = ws;                  // [1024][1024], dead after wx GEMM
  float* wx   = ws + (1 << 20);      // [16][1024][1024]

  float* gate = out;                 // park gate in d_out output region

  dim3 blk(256);
  // M1 = W_x @ in_proj_w   (folds in_proj into W_x: wx_all = x @ M1^T)
  gemm_nt<false, 0><<<dim3(16, 16), blk, 0, stream>>>(W_x, in_w, M1, 1024, 1024, 1024);
  // gate = silu(x @ gate_proj_w^T)
  gemm_nt<true, 1><<<dim3(16, 256), blk, 0, stream>>>(x, gate_w, gate, 16384, 1024, 1024);
  // wx_all = x @ M1^T
  gemm_nt<true, 0><<<dim3(16, 256), blk, 0, stream>>>(x, M1, wx, 16384, 1024, 1024);
  hipMemsetAsync(bar, 0, 2 * sizeof(int), stream);
  scan_kernel<<<256, 256, 0, stream>>>(W_h, W_wr, b_h, gate, wx, Rh_g, wv_g,
                                       p_r, p_w, hfin, tape, bar);
  // output = (h_all * gate) @ out_proj_w^T
  gemm_nt<true, 0><<<dim3(16, 256), blk, 0, stream>>>(wx, out_w, out, 16384, 1024, 1024);
}

// Round 3
// 39071.561 us; speedup vs baseline: 3.4041x; 2.1062x over previous
//
#include <hip/hip_runtime.h>
#include <math.h>

#define SCALE_F 0.03125f   // 1/sqrt(1024)

// =====================================================================
// fp32 tiled GEMM: C[M,N] = A[M,K] @ (BT ? B[N,K]^T : B[K,N])
// EPI: 0 = none, 1 = silu
// =====================================================================
template<bool BT, int EPI>
__global__ __launch_bounds__(256) void gemm_nt(const float* __restrict__ A,
                                               const float* __restrict__ Bm,
                                               float* __restrict__ C,
                                               int M, int N, int K) {
  __shared__ float As[32][68];
  __shared__ float Bs[32][68];
  const int tid = threadIdx.x;
  const int n0 = blockIdx.x * 64;
  const int m0 = blockIdx.y * 64;
  const int i0 = (tid >> 4) * 4;
  const int j0 = (tid & 15) * 4;
  float acc[4][4] = {};

  for (int k0 = 0; k0 < K; k0 += 32) {
#pragma unroll
    for (int s = 0; s < 2; ++s) {
      int id = tid + 256 * s;
      int r = id >> 3, c4 = id & 7;
      float4 v = *(const float4*)&A[(size_t)(m0 + r) * K + k0 + c4 * 4];
      As[c4 * 4 + 0][r] = v.x; As[c4 * 4 + 1][r] = v.y;
      As[c4 * 4 + 2][r] = v.z; As[c4 * 4 + 3][r] = v.w;
    }
    if (BT) {
#pragma unroll
      for (int s = 0; s < 2; ++s) {
        int id = tid + 256 * s;
        int r = id >> 3, c4 = id & 7;
        float4 v = *(const float4*)&Bm[(size_t)(n0 + r) * K + k0 + c4 * 4];
        Bs[c4 * 4 + 0][r] = v.x; Bs[c4 * 4 + 1][r] = v.y;
        Bs[c4 * 4 + 2][r] = v.z; Bs[c4 * 4 + 3][r] = v.w;
      }
    } else {
#pragma unroll
      for (int s = 0; s < 2; ++s) {
        int id = tid + 256 * s;
        int kk = id >> 4, c4 = id & 15;
        float4 v = *(const float4*)&Bm[(size_t)(k0 + kk) * N + n0 + c4 * 4];
        *(float4*)&Bs[kk][c4 * 4] = v;
      }
    }
    __syncthreads();
#pragma unroll
    for (int kk = 0; kk < 32; ++kk) {
      float4 a = *(const float4*)&As[kk][i0];
      float4 b = *(const float4*)&Bs[kk][j0];
      float av[4] = {a.x, a.y, a.z, a.w};
      float bv[4] = {b.x, b.y, b.z, b.w};
#pragma unroll
      for (int ii = 0; ii < 4; ++ii)
#pragma unroll
        for (int jj = 0; jj < 4; ++jj)
          acc[ii][jj] = fmaf(av[ii], bv[jj], acc[ii][jj]);
    }
    __syncthreads();
  }

#pragma unroll
  for (int ii = 0; ii < 4; ++ii) {
    float4 v;
    float* vp = (float*)&v;
#pragma unroll
    for (int jj = 0; jj < 4; ++jj) {
      float x = acc[ii][jj];
      if (EPI == 1) x = x / (1.0f + __expf(-x));
      vp[jj] = x;
    }
    *(float4*)&C[(size_t)(m0 + i0 + ii) * N + n0 + j0] = v;
  }
}

// =====================================================================
// Coherent (sc1) helpers: all cross-wg data goes through these.
// =====================================================================
__device__ __forceinline__ float ald(const float* p) {
  return __hip_atomic_load(p, __ATOMIC_RELAXED, __HIP_MEMORY_SCOPE_AGENT);
}
__device__ __forceinline__ void ast(float* p, float v) {
  __hip_atomic_store(p, v, __ATOMIC_RELAXED, __HIP_MEMORY_SCOPE_AGENT);
}
__device__ __forceinline__ int ildi(const int* p) {
  return __hip_atomic_load(p, __ATOMIC_RELAXED, __HIP_MEMORY_SCOPE_AGENT);
}

// Hierarchical grid barrier: 256 wgs = 16 leaves x 16.
// bar ints: leaf[l] at l*16 (l<16); root at 256; rgen at 272; lgen[l] at 288+l*16.
// Monotonic counters, no resets. Data coherence: all shared data uses sc1
// atomics, so only ordering needed = waitcnt before arrival.
__device__ __forceinline__ void gbar(int* bar, int wg, int* ep) {
  ++(*ep);
  const int target = *ep;
  __syncthreads();
  if (threadIdx.x == 0) {
    asm volatile("s_waitcnt vmcnt(0) lgkmcnt(0)" ::: "memory");
    int a = atomicAdd(&bar[(wg >> 4) * 16], 1);
    if ((a & 15) == 15) {
      int r = atomicAdd(&bar[256], 1);
      if ((r & 15) == 15) atomicAdd(&bar[272], 1);
    }
    if ((wg & 15) == 0) {
      while (ildi(&bar[272]) < target) __builtin_amdgcn_s_sleep(2);
      atomicAdd(&bar[288 + (wg >> 4) * 16], 1);
    } else {
      while (ildi(&bar[288 + (wg >> 4) * 16]) < target) __builtin_amdgcn_s_sleep(2);
    }
  }
  __syncthreads();
}

// Rotated tape addressing: row- and column-direction both conflict-free-ish.
#define TIDX(n, e) ((n) * 64 + (((e) + (n)) & 63))

// =====================================================================
// Persistent scan: 256 wgs x 256 threads (1/CU).
// wg -> owner role (b = wg>>4, es = wg&15): tape[b][all 64 n][64-e slice] in
// LDS; computes h[b][slice]. Matvec role: rows [4wg,4wg+4) of W_h (waves 0,1)
// and W_write (waves 2,3) in registers; lane covers d = j*256 + lane*4 + i.
// Two grid barriers per step:
//   Phase2: stage h, matvecs -> Rh, wv; reduce score partials -> ws. BAR.
//   Phase1: wa=softmax(ws); q=h.wv; rs=(1-wa)ws+wa q (identity); attn=
//           softmax(rs); tape lerp; gather; h(next)=tanh(...); publish
//           h + score partials vs updated tape. BAR.
// =====================================================================
__global__ __launch_bounds__(256, 1) void scan_kernel(
    const float* __restrict__ W_h, const float* __restrict__ W_wr,
    const float* __restrict__ b_h, const float* __restrict__ gate,
    float* __restrict__ wx,      // [B][T][D]; rows overwritten with h*gate
    float* __restrict__ Rh_g,    // [B][D]
    float* __restrict__ wv_g,    // [B][D]
    float* __restrict__ ps_g,    // [B][16][64] score partials
    float* __restrict__ h_g,     // [B][D] (= d_out h_work_f slot)
    float* __restrict__ tape_out,// [B][64][D]
    int* __restrict__ bar) {
  const int tid  = threadIdx.x;
  const int wg   = blockIdx.x;
  const int wave = tid >> 6;
  const int lane = tid & 63;
  const int b    = wg >> 4;
  const int es   = wg & 15;
  const int E0   = es * 64;
  int ep = 0;

  __shared__ float tape_l[64 * 64];   // rotated layout, 16 KB
  __shared__ float h_lds[16 * 1024];  // staged h, 64 KB
  __shared__ float ws_lds[64], wa_lds[64], attn_lds[64];
  __shared__ float wv_lds[64], h_own[64], Rh_lds[64];
  __shared__ float gath[4 * 64];
  __shared__ float q_lds;

  // ---- weight preload (permuted d-order: d = jj*256 + lane*4 + i) ----
  const float* Wmat = (wave < 2) ? W_h : W_wr;
  const int r0 = wg * 4 + (wave & 1) * 2;
  float w0[16], w1[16];
#pragma unroll
  for (int jj = 0; jj < 4; ++jj) {
    *(float4*)&w0[4 * jj] = *(const float4*)&Wmat[(size_t)r0 * 1024 + jj * 256 + lane * 4];
    *(float4*)&w1[4 * jj] = *(const float4*)&Wmat[(size_t)(r0 + 1) * 1024 + jj * 256 + lane * 4];
  }

  // ---- init: zero tape; prologue j=0: h1 = tanh(wx0 + b) ----
  for (int i = tid; i < 4096; i += 256) tape_l[i] = 0.0f;
  __syncthreads();
  if (wave == 0) {
    int e = E0 + lane;
    size_t xi = (size_t)b * 1048576 + e;           // wx[b][0][e]
    float hv = tanhf(wx[xi] + b_h[e]);
    h_own[lane] = hv;
    ast(&h_g[b * 1024 + e], hv);
    wx[xi] = hv * gate[xi];                        // output row 0
  }
  if ((tid & 3) == 0)                              // ps (vs tape0=0) = 0
    ast(&ps_g[b * 1024 + es * 64 + (tid >> 2)], 0.0f);
  gbar(bar, wg, &ep);

  for (int j = 1; j <= 1024; ++j) {
    const bool last = (j == 1024);
    // ================= Phase2: matvec =================
    // stage h(j) full (sc1 scalar loads -> LDS)
#pragma unroll
    for (int i = 0; i < 64; ++i) {
      int idx = tid + i * 256;
      h_lds[idx] = ald(&h_g[idx]);
    }
    __syncthreads();
    {
      float accA[16], accB[16];
#pragma unroll
      for (int bb = 0; bb < 16; ++bb) { accA[bb] = 0.0f; accB[bb] = 0.0f; }
#pragma unroll
      for (int bb = 0; bb < 16; ++bb) {
        const float* hb = &h_lds[bb * 1024 + lane * 4];
#pragma unroll
        for (int jj = 0; jj < 4; ++jj) {
          float4 hx = *(const float4*)&hb[jj * 256];
          float a = accA[bb], c = accB[bb];
          a = fmaf(w0[4 * jj + 0], hx.x, a); a = fmaf(w0[4 * jj + 1], hx.y, a);
          a = fmaf(w0[4 * jj + 2], hx.z, a); a = fmaf(w0[4 * jj + 3], hx.w, a);
          c = fmaf(w1[4 * jj + 0], hx.x, c); c = fmaf(w1[4 * jj + 1], hx.y, c);
          c = fmaf(w1[4 * jj + 2], hx.z, c); c = fmaf(w1[4 * jj + 3], hx.w, c);
          accA[bb] = a; accB[bb] = c;
        }
      }
#pragma unroll
      for (int off = 1; off < 64; off <<= 1) {
#pragma unroll
        for (int bb = 0; bb < 16; ++bb) {
          accA[bb] += __shfl_xor(accA[bb], off);
          accB[bb] += __shfl_xor(accB[bb], off);
        }
      }
      if (lane == 0) {
        float* dst = (wave < 2) ? Rh_g : wv_g;
#pragma unroll
        for (int bb = 0; bb < 16; ++bb) {
          ast(&dst[bb * 1024 + r0], accA[bb]);
          ast(&dst[bb * 1024 + r0 + 1], accB[bb]);
        }
      }
    }
    // reduce score partials ws = h(j).tape(j-1) (raw dot)
    if (wave == 0) {
      float s = 0.0f;
#pragma unroll
      for (int e2 = 0; e2 < 16; ++e2) s += ald(&ps_g[b * 1024 + e2 * 64 + lane]);
      ws_lds[lane] = s;
    }
    gbar(bar, wg, &ep);

    // ================= Phase1: attention + tape + h(j+1) =================
    if (wave == 0) {           // wa = softmax(SCALE*ws)
      float s = ws_lds[lane] * SCALE_F;
      float m = s;
#pragma unroll
      for (int off = 1; off < 64; off <<= 1) m = fmaxf(m, __shfl_xor(m, off));
      float ex = __expf(s - m);
      float sum = ex;
#pragma unroll
      for (int off = 1; off < 64; off <<= 1) sum += __shfl_xor(sum, off);
      wa_lds[lane] = ex / sum;
    } else if (wave == 1) {    // q = h(j).wv  +  wv own slice
      float qp = 0.0f;
      const float* hb = &h_lds[b * 1024 + lane * 16];
#pragma unroll
      for (int ii = 0; ii < 16; ++ii)
        qp = fmaf(hb[ii], ald(&wv_g[b * 1024 + lane * 16 + ii]), qp);
#pragma unroll
      for (int off = 1; off < 64; off <<= 1) qp += __shfl_xor(qp, off);
      if (lane == 0) q_lds = qp;
      wv_lds[lane] = ald(&wv_g[b * 1024 + E0 + lane]);
    } else if (wave == 2) {
      Rh_lds[lane] = ald(&Rh_g[b * 1024 + E0 + lane]);
    }
    __syncthreads();
    if (wave == 0 && !last) {  // attn = softmax(SCALE*rs), rs via identity
      float wa = wa_lds[lane];
      float rs = ((1.0f - wa) * ws_lds[lane] + wa * q_lds) * SCALE_F;
      float m = rs;
#pragma unroll
      for (int off = 1; off < 64; off <<= 1) m = fmaxf(m, __shfl_xor(m, off));
      float ex = __expf(rs - m);
      float sum = ex;
#pragma unroll
      for (int off = 1; off < 64; off <<= 1) sum += __shfl_xor(sum, off);
      attn_lds[lane] = ex / sum;
    }
    __syncthreads();
    {  // tape lerp (+ gather partials)
      float wvv = wv_lds[lane];
      float g = 0.0f;
#pragma unroll
      for (int i = 0; i < 16; ++i) {
        int n = wave * 16 + i;
        float wa = wa_lds[n];
        float t = tape_l[TIDX(n, lane)];
        t += wa * (wvv - t);
        tape_l[TIDX(n, lane)] = t;
        if (!last) g = fmaf(attn_lds[n], t, g);
      }
      gath[wave * 64 + lane] = g;
    }
    __syncthreads();
    if (!last) {
      if (wave == 0) {
        int e = E0 + lane;
        size_t xi = (size_t)b * 1048576 + (size_t)j * 1024 + e;
        float rd = gath[lane] + gath[64 + lane] + gath[128 + lane] + gath[192 + lane];
        float hv = tanhf(Rh_lds[lane] + wx[xi] + rd + b_h[e]);
        h_own[lane] = hv;
        ast(&h_g[b * 1024 + e], hv);
        wx[xi] = hv * gate[xi];
      }
      __syncthreads();
      {  // score partials vs updated tape: ps[n] = sum_own_e h(j+1).tape(j)
        int n = tid >> 2, eq = tid & 3;
        float s = 0.0f;
#pragma unroll
        for (int jj2 = 0; jj2 < 16; ++jj2) {
          int e = eq * 16 + jj2;
          s = fmaf(h_own[e], tape_l[TIDX(n, e)], s);
        }
        s += __shfl_xor(s, 1);
        s += __shfl_xor(s, 2);
        if (eq == 0) ast(&ps_g[b * 1024 + es * 64 + n], s);
      }
      gbar(bar, wg, &ep);
    }
  }

  // ---- epilogue: dump final tape ----
#pragma unroll
  for (int i = 0; i < 16; ++i) {
    int n = wave * 16 + i;
    tape_out[(size_t)(b * 64 + n) * 1024 + E0 + lane] = tape_l[TIDX(n, lane)];
  }
}

// =====================================================================
extern "C" void kernel_launch(void* const* d_in, const int* in_sizes, int n_in,
                              void* d_out, int out_size, void* d_ws, size_t ws_size,
                              hipStream_t stream) {
  (void)in_sizes; (void)n_in; (void)out_size; (void)ws_size;
  const float* x      = (const float*)d_in[0];
  const float* in_w   = (const float*)d_in[1];
  const float* out_w  = (const float*)d_in[2];
  const float* gate_w = (const float*)d_in[3];
  const float* W_x    = (const float*)d_in[4];
  const float* W_h    = (const float*)d_in[5];
  const float* W_wr   = (const float*)d_in[6];
  const float* b_h    = (const float*)d_in[7];

  float* out  = (float*)d_out;                     // [16][1024][1024]
  float* tape = out + (size_t)16 * 1024 * 1024;    // [16][64][1024]
  float* hfin = tape + (size_t)16 * 64 * 1024;     // [16][1024]

  float* ws = (float*)d_ws;
  // scan-time small buffers overlay M1's region (M1 dead before scan)
  float* Rh_g = ws;                  // 16384
  float* wv_g = ws + 16384;          // 16384
  float* ps_g = ws + 32768;          // 16384
  int*   bar  = (int*)(ws + 49152);  // ~544 ints used
  float* M1   = ws;                  // [1024][1024]
  float* wx   = ws + (1 << 20);      // [16][1024][1024]

  float* gate = out;                 // park gate in d_out region

  dim3 blk(256);
  gemm_nt<false, 0><<<dim3(16, 16), blk, 0, stream>>>(W_x, in_w, M1, 1024, 1024, 1024);
  gemm_nt<true, 1><<<dim3(16, 256), blk, 0, stream>>>(x, gate_w, gate, 16384, 1024, 1024);
  gemm_nt<true, 0><<<dim3(16, 256), blk, 0, stream>>>(x, M1, wx, 16384, 1024, 1024);
  hipMemsetAsync(bar, 0, 4096, stream);
  scan_kernel<<<256, 256, 0, stream>>>(W_h, W_wr, b_h, gate, wx, Rh_g, wv_g,
                                       ps_g, hfin, tape, bar);
  gemm_nt<true, 0><<<dim3(16, 256), blk, 0, stream>>>(wx, out_w, out, 16384, 1024, 1024);
}